// Round 12
// baseline (297.144 us; speedup 1.0000x reference)
//
#include <hip/hip_runtime.h>
#include <cstdint>

#define N_PTS 2097152          // 2^21
#define MASK  (N_PTS - 1)

constexpr int NPOS = 128;      // grid positions per block (pos q in [0,128))
constexpr int POUT = 116;      // outputs per block: g = i0 + tid, tid < 116
constexpr int GOFF = 6;        // g = i0 - GOFF + q
constexpr int BLK  = 256;      // 4 waves; each wave owns TWO 16-pos n-tiles
constexpr int NBLK = (N_PTS + POUT - 1) / POUT;   // 18079 real blocks (+1 tail)

// LDS activation strides (u16 units); row stride = odd multiple of 16 B
constexpr int ST1 = 40;    // act1: 20 ch + bias col 20 (k-pad 32), 128 rows
constexpr int ST2 = 72;    // act2: 40 ch + bias col 40 (k-pad 64), 128 rows
constexpr int ST3 = 104;   // act3: 80 ch + bias col 80 (k-pad 96), 128 rows
constexpr int ST4 = 72;    // act4: 40 ch + bias col 40 (k-pad 64), 130 rows (q off +1)

constexpr int SLOTA_OFF = 0;
constexpr int SLOTA_SZ  = 128 * ST3 * 2;            // 26624 B (act1 / act3)
constexpr int SLOTB_OFF = SLOTA_SZ;
constexpr int SLOTB_SZ  = 130 * ST4 * 2;            // 18720 B (act2 / act4)
constexpr int TAIL_OFF  = SLOTB_OFF + SLOTB_SZ;     // 45344
// tail f32: sdif 132 | sw6 20 | sb6 1 | sbm 118 | su 121 = 392
constexpr int SMEM_BYTES = TAIL_OFF + 392 * 4;      // 46912 -> 3 blocks/CU

// precomputed bf16 A-fragments in d_ws (u16 units); frag idx = (t*MT+mt)*KS+ks
constexpr int F2 = 0;          // L2: 5 taps x MT3 x KS1 = 15 frags x 512 u16
constexpr int F3 = 7680;       // L3: 1 x 5 x 2 = 10
constexpr int F4 = 12800;      // L4: 1 x 3 x 3 = 9
constexpr int F5 = 17408;      // L5: 3 x 2 x 2 = 12
constexpr int F1 = 23552;      // L1: 2 frags (MT=2, taps+bias in k)  -> ends 24576
constexpr int NFRAG2 = 15, NFRAG3 = 10, NFRAG4 = 9, NFRAG5 = 12;
constexpr int NPREP = NFRAG2 + NFRAG3 + NFRAG4 + NFRAG5 + 2;   // 48
constexpr int BME_OFF = 65536; // 4 edge bm values (f32): bm[0], bm[1], bm[N-2], bm[N-1]
                               // 0 = "not ready" (bmv > 0.1 always; prep zeroes)

typedef __bf16 bf16x8 __attribute__((ext_vector_type(8)));
typedef unsigned short u16x8 __attribute__((ext_vector_type(8)));
typedef float f32x4 __attribute__((ext_vector_type(4)));

constexpr unsigned short BF16_ONE = 0x3F80;

__device__ __forceinline__ float elu(float x) { return x > 0.f ? x : __expf(x) - 1.f; }

__device__ __forceinline__ float fastrcp(float x) {
#if __has_builtin(__builtin_amdgcn_rcpf)
    return __builtin_amdgcn_rcpf(x);
#else
    return 1.f / x;
#endif
}

// precise RTNE (weights, once in prep)
__device__ __forceinline__ unsigned short f2b_rtne(float f) {
    union { float f; unsigned int u; } x; x.f = f;
    return (unsigned short)((x.u + 0x7fffu + ((x.u >> 16) & 1u)) >> 16);
}
// pack two f32 -> two bf16 (round-half-up) in one dword
__device__ __forceinline__ unsigned int pack_bf16_2(float lo, float hi) {
#if __has_builtin(__builtin_amdgcn_perm)
    union { float f; unsigned int u; } a, b;
    a.f = lo; b.f = hi;
    return __builtin_amdgcn_perm(b.u + 0x8000u, a.u + 0x8000u, 0x07060302u);
#else
    union { float f; unsigned int u; } a, b;
    a.f = lo; b.f = hi;
    return ((a.u + 0x8000u) >> 16) | (((b.u + 0x8000u) >> 16) << 16);
#endif
}

// ---------------------------------------------------------------------------
// Prep: one fragment per block. RTNE, zero-padded m/k.
// Bias folded at k == CI on tap biasTap (activation bias column holds 1.0).
// Block 0 also zeroes the bmE ready-slots (re-armed every launch).
// ---------------------------------------------------------------------------
template<int M, int MT, int CI, int KS, int KT>
__device__ __forceinline__ void pack_one(const float* __restrict__ W,
                                         const float* __restrict__ Bias, int biasTap,
                                         unsigned short* __restrict__ dst,
                                         int f, int lane)
{
    const int ks = f % KS;
    const int fi = f / KS;
    const int mt = fi % MT;
    const int t  = fi / MT;
    const int m  = mt * 16 + (lane & 15);
    const int kb = ks * 32 + (lane >> 4) * 8;
    u16x8 v;
    #pragma unroll
    for (int j = 0; j < 8; ++j) {
        const int k = kb + j;
        float val = 0.f;
        if (m < M) {
            if (k < CI)                          val = W[(m * CI + k) * KT + t];
            else if (k == CI && t == biasTap)    val = Bias[m];
        }
        v[j] = f2b_rtne(val);
    }
    *(u16x8*)(dst + (f * 64 + lane) * 8) = v;
}

__global__ __launch_bounds__(64) void prep_kernel(
    const float* __restrict__ w1, const float* __restrict__ b1,
    const float* __restrict__ w2, const float* __restrict__ b2,
    const float* __restrict__ w3, const float* __restrict__ b3,
    const float* __restrict__ w4, const float* __restrict__ b4,
    const float* __restrict__ w5, const float* __restrict__ b5,
    unsigned short* __restrict__ frags,
    float* __restrict__ bmE)
{
    const int lane = threadIdx.x;
    const int b = blockIdx.x;
    if (b == 0 && lane < 4) bmE[lane] = 0.f;   // "not ready" sentinel
    if (b < NFRAG2)
        pack_one<40, 3, 20, 1, 5>(w2, b2, 2, frags + F2, b, lane);
    else if (b < NFRAG2 + NFRAG3)
        pack_one<80, 5, 40, 2, 1>(w3, b3, 0, frags + F3, b - NFRAG2, lane);
    else if (b < NFRAG2 + NFRAG3 + NFRAG4)
        pack_one<40, 3, 80, 3, 1>(w4, b4, 0, frags + F4, b - NFRAG2 - NFRAG3, lane);
    else if (b < NFRAG2 + NFRAG3 + NFRAG4 + NFRAG5)
        pack_one<20, 2, 40, 2, 3>(w5, b5, 1, frags + F5, b - NFRAG2 - NFRAG3 - NFRAG4, lane);
    else {
        // L1 fragments: A[m][k], k=0..4 -> w1 taps, k=5 -> bias, else 0; im2col B.
        const int mt = b - (NPREP - 2);
        const int m  = mt * 16 + (lane & 15);
        const int kb = (lane >> 4) * 8;
        u16x8 v;
        #pragma unroll
        for (int j = 0; j < 8; ++j) {
            const int k = kb + j;
            float val = 0.f;
            if (m < 20) {
                if (k < 5)      val = w1[m * 5 + k];
                else if (k == 5) val = b1[m];
            }
            v[j] = f2b_rtne(val);
        }
        *(u16x8*)(frags + F1 + (mt * 64 + lane) * 8) = v;
    }
}

// ---------------------------------------------------------------------------
// Tap-decomposed MFMA layer; wave wv owns n-tiles 2wv, 2wv+1.
// A-fragments preloaded to registers. First MFMA consumes the hoisted Z4 quad
// (no per-accumulator zero materialization). Bias via the 1.0 column.
// ---------------------------------------------------------------------------
template<int TAPS, int MT, int KS, typename Epi>
__device__ __forceinline__ void gemm_tap(const unsigned short* __restrict__ Af,
                                         const unsigned short* __restrict__ Bbuf,
                                         int SB, f32x4 Z4, Epi epi)
{
    const int lane = threadIdx.x & 63;
    const int wv   = threadIdx.x >> 6;
    const int n15  = lane & 15;
    const int quad = lane >> 4;

    bf16x8 A[TAPS * MT * KS];
    #pragma unroll
    for (int f = 0; f < TAPS * MT * KS; ++f)
        A[f] = __builtin_bit_cast(bf16x8, *(const u16x8*)(Af + (f * 64 + lane) * 8));

    #pragma unroll
    for (int nt = 0; nt < 2; ++nt) {
        const int pos = (wv * 2 + nt) * 16 + n15;
        bf16x8 B[TAPS][KS];
        #pragma unroll
        for (int t = 0; t < TAPS; ++t)
            #pragma unroll
            for (int ks = 0; ks < KS; ++ks)
                B[t][ks] = __builtin_bit_cast(bf16x8,
                    *(const u16x8*)(Bbuf + (pos + t) * SB + ks * 32 + quad * 8));
        #pragma unroll
        for (int mt = 0; mt < MT; ++mt) {
            f32x4 acc = __builtin_amdgcn_mfma_f32_16x16x32_bf16(
                A[mt * KS], B[0][0], Z4, 0, 0, 0);
            #pragma unroll
            for (int i = 1; i < TAPS * KS; ++i) {
                const int t = i / KS, ks = i - t * KS;
                acc = __builtin_amdgcn_mfma_f32_16x16x32_bf16(
                    A[(t * MT + mt) * KS + ks], B[t][ks], acc, 0, 0, 0);
            }
            epi(mt, pos, acc);
        }
    }
}

// ---------------------------------------------------------------------------
// WENO5 math given the 6-point u stencil and 3 bm values (rcp-based)
// ---------------------------------------------------------------------------
__device__ __forceinline__ float weno_math(float um2, float um1, float u0,
                                           float up1, float up2, float up3,
                                           float bmm, float bm0, float bmp)
{
    const float c1312 = 13.f / 12.f;
    const float s6 = 1.f / 6.f;

    const float f0p = (11.f * up1 - 7.f * up2 + 2.f * up3) * s6;
    const float f1p = (2.f * u0 + 5.f * up1 - up2) * s6;
    const float f2p = (-um1 + 5.f * u0 + 2.f * up1) * s6;
    const float f0n = (11.f * u0 - 7.f * up1 + 2.f * up2) * s6;
    const float f1n = (2.f * um1 + 5.f * u0 - up1) * s6;
    const float f2n = (-um2 + 5.f * um1 + 2.f * u0) * s6;

    float t0, t1;
    t0 = up1 - 2.f * up2 + up3;  t1 = 3.f * up1 - 4.f * up2 + up3;
    float bp0 = c1312 * t0 * t0 + 0.25f * t1 * t1;
    t0 = u0 - 2.f * up1 + up2;   t1 = u0 - up2;
    float bp1 = c1312 * t0 * t0 + 0.25f * t1 * t1;
    t0 = um1 - 2.f * u0 + up1;   t1 = um1 - 4.f * u0 + 3.f * up1;
    float bp2 = c1312 * t0 * t0 + 0.25f * t1 * t1;
    t0 = u0 - 2.f * up1 + up2;   t1 = 3.f * u0 - 4.f * up1 + up2;
    float bn0 = c1312 * t0 * t0 + 0.25f * t1 * t1;
    t0 = um1 - 2.f * u0 + up1;   t1 = um1 - up1;
    float bn1 = c1312 * t0 * t0 + 0.25f * t1 * t1;
    t0 = um2 - 2.f * um1 + u0;   t1 = um2 - 4.f * um1 + 3.f * u0;
    float bn2 = c1312 * t0 * t0 + 0.25f * t1 * t1;

    bp0 *= bmp; bp1 *= bm0; bp2 *= bmm;
    bn0 *= bmp; bn1 *= bm0; bn2 *= bmm;

    const float E = 1e-13f;
    float brs, e, r0, r1, r2, o0, o1, o2;

    brs = bp2 - bp0; brs *= brs;
    e = E + bp0; e *= e; r0 = fastrcp(e);
    e = E + bp1; e *= e; r1 = fastrcp(e);
    e = E + bp2; e *= e; r2 = fastrcp(e);
    o0 = 0.1f * fmaf(brs, r0, 1.f);
    o1 = 0.6f * fmaf(brs, r1, 1.f);
    o2 = 0.3f * fmaf(brs, r2, 1.f);
    const float fluxp = (o0 * f0p + o1 * f1p + o2 * f2p) * fastrcp(o0 + o1 + o2);

    brs = bn2 - bn0; brs *= brs;
    e = E + bn0; e *= e; r0 = fastrcp(e);
    e = E + bn1; e *= e; r1 = fastrcp(e);
    e = E + bn2; e *= e; r2 = fastrcp(e);
    o0 = 0.1f * fmaf(brs, r0, 1.f);
    o1 = 0.6f * fmaf(brs, r1, 1.f);
    o2 = 0.3f * fmaf(brs, r2, 1.f);
    const float fluxn = (o0 * f0n + o1 * f1n + o2 * f2n) * fastrcp(o0 + o1 + o2);

    return fluxp - fluxn;
}

// ---------------------------------------------------------------------------
// Fused CNN + WENO (256 threads = 4 waves; two n-tiles per wave).
// Grid = NBLK + 1: the extra block is a zero-contention tail that waits for
// the 4 edge bm values and patches the two periodic-wrap outputs.
// ---------------------------------------------------------------------------
__global__ __launch_bounds__(BLK, 3) void cnn_weno_kernel(
    const float* __restrict__ u,
    const float* __restrict__ w6, const float* __restrict__ b6,
    const unsigned short* __restrict__ frags,
    float* __restrict__ bmE,
    float* __restrict__ out)
{
    // ---- tail block: spin on the 4 ready-slots, then patch wrap points ----
    if (blockIdx.x == NBLK) {
        if (threadIdx.x == 0) {
            float b0, b1, b2, b3;
            for (;;) {
                b0 = __hip_atomic_load(&bmE[0], __ATOMIC_ACQUIRE, __HIP_MEMORY_SCOPE_AGENT);
                b1 = __hip_atomic_load(&bmE[1], __ATOMIC_ACQUIRE, __HIP_MEMORY_SCOPE_AGENT);
                b2 = __hip_atomic_load(&bmE[2], __ATOMIC_ACQUIRE, __HIP_MEMORY_SCOPE_AGENT);
                b3 = __hip_atomic_load(&bmE[3], __ATOMIC_ACQUIRE, __HIP_MEMORY_SCOPE_AGENT);
                if (b0 != 0.f && b1 != 0.f && b2 != 0.f && b3 != 0.f) break;
                __builtin_amdgcn_s_sleep(2);
            }
            out[0] = weno_math(u[N_PTS - 2], u[N_PTS - 1], u[0],
                               u[1], u[2], u[3], b3, b0, b1);
            out[N_PTS - 1] = weno_math(u[N_PTS - 3], u[N_PTS - 2], u[N_PTS - 1],
                                       u[0], u[1], u[2], b2, b3, b0);
        }
        return;
    }

    extern __shared__ char smem[];
    unsigned short* act1 = (unsigned short*)(smem + SLOTA_OFF);  // [128][ST1]
    unsigned short* act3 = (unsigned short*)(smem + SLOTA_OFF);  // [128][ST3]
    unsigned short* act2 = (unsigned short*)(smem + SLOTB_OFF);  // [128][ST2]
    unsigned short* act4 = (unsigned short*)(smem + SLOTB_OFF);  // [130][ST4]
    float* sdif = (float*)(smem + TAIL_OFF);   // 132
    float* sw6  = sdif + 132;                  // 20
    float* sb6  = sw6 + 20;                    // 1
    float* sbm  = sb6 + 1;                     // 118  (sbm[j] = bm at q = j + 5)
    float* su   = sbm + 118;                   // 121  (su[j] = u[(i0-2+j) & MASK])

    const int tid  = threadIdx.x;
    const int lane = tid & 63;
    const int wv   = tid >> 6;
    const int n15  = lane & 15;
    const int quad = lane >> 4;
    const int i0   = blockIdx.x * POUT;
    const bool edge = (blockIdx.x == 0) || (blockIdx.x >= NBLK - 1);

    const f32x4 Z4 = {0.f, 0.f, 0.f, 0.f};     // hoisted zero C-operand

    // ---- phase 1: minimal pad init + staging ----
    {
        // SLOTB (act2/act4) cols 48..63 zero (rows 0..129)
        const u16x8 z8 = {0, 0, 0, 0, 0, 0, 0, 0};
        for (int i = tid; i < 130 * 2; i += BLK) {
            const int r = i >> 1, c = 48 + (i & 1) * 8;
            *(u16x8*)(act2 + r * ST2 + c) = z8;
        }
        // act3 cols 80..95 (bias col 80 = 1.0), rows 0..127
        for (int i = tid; i < 128 * 2; i += BLK) {
            const int r = i >> 1, j = i & 1;
            u16x8 v = {0, 0, 0, 0, 0, 0, 0, 0};
            if (j == 0) v[0] = BF16_ONE;
            *(u16x8*)(act3 + r * ST3 + 80 + j * 8) = v;
        }
    }
    if (!edge) {   // fast path: no boundary handling needed (uniform branch)
        for (int d = tid; d < 132; d += BLK) {
            const int g = i0 - 10 + d;
            sdif[d] = 0.5f * (u[g + 1] - u[g - 1]);
        }
        for (int j = tid; j < 121; j += BLK)
            su[j] = u[i0 - 2 + j];
    } else {
        for (int d = tid; d < 132; d += BLK) {
            const int g = i0 - 10 + d;
            float v = 0.f;
            if (g >= 0 && g < N_PTS) {
                if (g == 0)              v = u[1] - u[0];
                else if (g == N_PTS - 1) v = u[N_PTS - 1] - u[N_PTS - 2];
                else                     v = 0.5f * (u[g + 1] - u[g - 1]);
            }
            sdif[d] = v;
        }
        for (int j = tid; j < 121; j += BLK)
            su[j] = u[(i0 - 2 + j) & MASK];
    }
    if (tid < 20)       sw6[tid] = w6[tid];
    else if (tid == 20) sb6[0] = b6[0];
    __syncthreads();

    // ---- phase 2: L1 via MFMA (im2col B from sdif; taps+bias in k) ----
    {
        bf16x8 A1[2];
        #pragma unroll
        for (int f = 0; f < 2; ++f)
            A1[f] = __builtin_bit_cast(bf16x8,
                *(const u16x8*)(frags + F1 + (f * 64 + lane) * 8));
        #pragma unroll
        for (int nt = 0; nt < 2; ++nt) {
            const int pos = (wv * 2 + nt) * 16 + n15;
            const float s0 = sdif[pos],     s1 = sdif[pos + 1], s2 = sdif[pos + 2],
                        s3 = sdif[pos + 3], s4 = sdif[pos + 4];
            uint4 bd;
            bd.x = pack_bf16_2(s0, s1);
            bd.y = pack_bf16_2(s2, s3);
            bd.z = pack_bf16_2(s4, 1.0f);    // k=5 bias slot
            bd.w = 0u;
            const bf16x8 B = __builtin_bit_cast(bf16x8, bd);
            const f32x4 a0 = __builtin_amdgcn_mfma_f32_16x16x32_bf16(A1[0], B, Z4, 0, 0, 0);
            const f32x4 a1 = __builtin_amdgcn_mfma_f32_16x16x32_bf16(A1[1], B, Z4, 0, 0, 0);
            bool oor = false;
            if (edge) {
                const int g = i0 + pos - 8;   // act1 row pos <-> g
                oor = ((unsigned)g >= (unsigned)N_PTS);
            }
            {   // ch 0..15
                float v0 = elu(a0[0]), v1 = elu(a0[1]), v2 = elu(a0[2]), v3 = elu(a0[3]);
                if (oor) { v0 = v1 = v2 = v3 = 0.f; }
                uint2 w; w.x = pack_bf16_2(v0, v1); w.y = pack_bf16_2(v2, v3);
                *(uint2*)(act1 + pos * ST1 + quad * 4) = w;
            }
            {   // ch 16..19 + bias col 20 + zero pad 24..31
                uint2 w;
                if (quad == 0) {
                    float v0 = elu(a1[0]), v1 = elu(a1[1]), v2 = elu(a1[2]), v3 = elu(a1[3]);
                    if (oor) { v0 = v1 = v2 = v3 = 0.f; }
                    w.x = pack_bf16_2(v0, v1); w.y = pack_bf16_2(v2, v3);
                } else if (quad == 1) {
                    w.x = (unsigned)BF16_ONE; w.y = 0u;
                } else {
                    w.x = 0u; w.y = 0u;
                }
                *(uint2*)(act1 + pos * ST1 + 16 + quad * 4) = w;
            }
        }
    }
    __syncthreads();

    // ---- phase 3: L2 (40ch, 5 taps, bias folded) act1 -> act2 ----
    // B rows pos+t up to 131 read stale LDS; contaminates only bm[pos>=123],
    // which is never consumed (sbm range is pos in [5,123)).
    gemm_tap<5, 3, 1>(frags + F2, act1, ST1, Z4,
        [&](int mt, int pos, f32x4 acc) {
            const int ch0 = mt * 16 + quad * 4;
            unsigned short* dst = act2 + pos * ST2 + ch0;
            if (mt < 2 || quad < 2) {
                float v0 = elu(acc[0]), v1 = elu(acc[1]), v2 = elu(acc[2]), v3 = elu(acc[3]);
                if (edge) {
                    const int g = i0 - GOFF + pos;
                    if ((unsigned)g >= (unsigned)N_PTS) { v0 = v1 = v2 = v3 = 0.f; }
                }
                uint2 w; w.x = pack_bf16_2(v0, v1); w.y = pack_bf16_2(v2, v3);
                *(uint2*)dst = w;
            } else {   // ch 40 bias col + zeros 41..47
                uint2 w; w.x = (quad == 2) ? (unsigned)BF16_ONE : 0u; w.y = 0u;
                *(uint2*)dst = w;
            }
        });
    __syncthreads();

    // ---- phase 4: L3 (80ch, k=1, bias folded) act2 -> act3 ----
    gemm_tap<1, 5, 2>(frags + F3, act2, ST2, Z4,
        [&](int mt, int pos, f32x4 acc) {
            const int ch0 = mt * 16 + quad * 4;
            float v0 = elu(acc[0]), v1 = elu(acc[1]), v2 = elu(acc[2]), v3 = elu(acc[3]);
            if (edge) {
                const int g = i0 - GOFF + pos;
                if ((unsigned)g >= (unsigned)N_PTS) { v0 = v1 = v2 = v3 = 0.f; }
            }
            uint2 w; w.x = pack_bf16_2(v0, v1); w.y = pack_bf16_2(v2, v3);
            *(uint2*)(act3 + pos * ST3 + ch0) = w;
        });
    __syncthreads();

    // ---- phase 5: L4 (40ch, k=1, bias folded) act3 -> act4 (row off +1) ----
    gemm_tap<1, 3, 3>(frags + F4, act3, ST3, Z4,
        [&](int mt, int pos, f32x4 acc) {
            const int ch0 = mt * 16 + quad * 4;
            unsigned short* dst = act4 + (pos + 1) * ST4 + ch0;
            if (mt < 2 || quad < 2) {
                float v0 = elu(acc[0]), v1 = elu(acc[1]), v2 = elu(acc[2]), v3 = elu(acc[3]);
                if (edge) {
                    const int g = i0 - GOFF + pos;
                    if ((unsigned)g >= (unsigned)N_PTS) { v0 = v1 = v2 = v3 = 0.f; }
                }
                uint2 w; w.x = pack_bf16_2(v0, v1); w.y = pack_bf16_2(v2, v3);
                *(uint2*)dst = w;
            } else {
                uint2 w; w.x = (quad == 2) ? (unsigned)BF16_ONE : 0u; w.y = 0u;
                *(uint2*)dst = w;
            }
        });
    __syncthreads();

    // ---- phase 6: L5 (20ch, 3 taps, bias folded) + L6 + sigmoid -> sbm ----
    {
        const unsigned short* Af = frags + F5;
        bf16x8 A5[12];
        #pragma unroll
        for (int f = 0; f < 12; ++f)
            A5[f] = __builtin_bit_cast(bf16x8, *(const u16x8*)(Af + (f * 64 + lane) * 8));

        #pragma unroll
        for (int nt = 0; nt < 2; ++nt) {
            const int pos = (wv * 2 + nt) * 16 + n15;
            bf16x8 B[3][2];
            #pragma unroll
            for (int t = 0; t < 3; ++t)
                #pragma unroll
                for (int ks = 0; ks < 2; ++ks)
                    B[t][ks] = __builtin_bit_cast(bf16x8,
                        *(const u16x8*)(act4 + (pos + t) * ST4 + ks * 32 + quad * 8));
            f32x4 a0 = __builtin_amdgcn_mfma_f32_16x16x32_bf16(A5[0], B[0][0], Z4, 0, 0, 0);
            f32x4 a1 = __builtin_amdgcn_mfma_f32_16x16x32_bf16(A5[2], B[0][0], Z4, 0, 0, 0);
            #pragma unroll
            for (int i = 1; i < 6; ++i) {
                const int t = i >> 1, ks = i & 1;
                a0 = __builtin_amdgcn_mfma_f32_16x16x32_bf16(
                    A5[(t * 2 + 0) * 2 + ks], B[t][ks], a0, 0, 0, 0);
                a1 = __builtin_amdgcn_mfma_f32_16x16x32_bf16(
                    A5[(t * 2 + 1) * 2 + ks], B[t][ks], a1, 0, 0, 0);
            }
            float partial = 0.f;
            const int c0 = quad * 4;
            #pragma unroll
            for (int r = 0; r < 4; ++r)
                partial += sw6[c0 + r] * elu(a0[r]);
            if (quad == 0) {
                #pragma unroll
                for (int r = 0; r < 4; ++r)
                    partial += sw6[16 + r] * elu(a1[r]);
            }
            partial += __shfl_xor(partial, 16, 64);
            partial += __shfl_xor(partial, 32, 64);
            if (quad == 0) {
                const float bmv = fastrcp(1.f + __expf(-(partial + sb6[0]))) + 0.1f;
                if (pos >= 5 && pos < 123) sbm[pos - 5] = bmv;
                if (edge) {
                    const int g = i0 - GOFF + pos;
                    if (blockIdx.x == 0) {
                        if (g == 0)
                            __hip_atomic_store(&bmE[0], bmv, __ATOMIC_RELEASE, __HIP_MEMORY_SCOPE_AGENT);
                        else if (g == 1)
                            __hip_atomic_store(&bmE[1], bmv, __ATOMIC_RELEASE, __HIP_MEMORY_SCOPE_AGENT);
                    }
                    if (blockIdx.x == NBLK - 1) {
                        if (g == N_PTS - 2)
                            __hip_atomic_store(&bmE[2], bmv, __ATOMIC_RELEASE, __HIP_MEMORY_SCOPE_AGENT);
                        else if (g == N_PTS - 1)
                            __hip_atomic_store(&bmE[3], bmv, __ATOMIC_RELEASE, __HIP_MEMORY_SCOPE_AGENT);
                    }
                }
            }
        }
    }
    __syncthreads();

    // ---- phase 7: WENO from the staged u tile (wrap handled at staging) ----
    if (tid < POUT) {
        const int g = i0 + tid;
        if (g < N_PTS && g != 0 && g != N_PTS - 1) {
            out[g] = weno_math(su[tid], su[tid + 1], su[tid + 2],
                               su[tid + 3], su[tid + 4], su[tid + 5],
                               sbm[tid], sbm[tid + 1], sbm[tid + 2]);
        }
    }
}

extern "C" void kernel_launch(void* const* d_in, const int* in_sizes, int n_in,
                              void* d_out, int out_size, void* d_ws, size_t ws_size,
                              hipStream_t stream) {
    const float* u  = (const float*)d_in[0];
    const float* w1 = (const float*)d_in[1];
    const float* b1 = (const float*)d_in[2];
    const float* w2 = (const float*)d_in[3];
    const float* b2 = (const float*)d_in[4];
    const float* w3 = (const float*)d_in[5];
    const float* b3 = (const float*)d_in[6];
    const float* w4 = (const float*)d_in[7];
    const float* b4 = (const float*)d_in[8];
    const float* w5 = (const float*)d_in[9];
    const float* b5 = (const float*)d_in[10];
    const float* w6 = (const float*)d_in[11];
    const float* b6 = (const float*)d_in[12];

    unsigned short* frags = (unsigned short*)d_ws;            // 49152 B
    float* bmE = (float*)((char*)d_ws + BME_OFF);             // 4 f32 ready-slots

    (void)hipFuncSetAttribute((const void*)cnn_weno_kernel,
                              hipFuncAttributeMaxDynamicSharedMemorySize,
                              SMEM_BYTES);

    prep_kernel<<<NPREP, 64, 0, stream>>>(w1, b1, w2, b2, w3, b3, w4, b4, w5, b5,
                                          frags, bmE);
    cnn_weno_kernel<<<NBLK + 1, BLK, SMEM_BYTES, stream>>>(u, w6, b6, frags, bmE,
                                                           (float*)d_out);
}

// Round 14
// 280.714 us; speedup vs baseline: 1.0585x; 1.0585x over previous
//
#include <hip/hip_runtime.h>
#include <cstdint>

#define N_PTS 2097152          // 2^21
#define MASK  (N_PTS - 1)

constexpr int NPOS = 128;      // grid positions per block (pos q in [0,128))
constexpr int POUT = 116;      // outputs per block: g = i0 + tid, tid < 116
constexpr int GOFF = 6;        // g = i0 - GOFF + q
constexpr int BLK  = 256;      // 4 waves; each wave owns TWO 16-pos n-tiles
constexpr int NBLK = (N_PTS + POUT - 1) / POUT;   // 18079 real blocks (+1 tail)

// LDS activation strides (u16 units); stride = odd multiple of 16 B (2-way-free).
// k-pad columns beyond bias only need to be FINITE (A-weights are zero there);
// ks-tail reads spill into the next row. ALL stale-read targets are zeroed in
// phase 1 (virgin-LDS NaN immunity — see R13 post-mortem).
constexpr int ST1 = 40;    // act1: 20 ch + bias col 20, rows 0..131 (128..131 zeroed)
constexpr int ST2 = 56;    // act2: 40 ch + bias col 40 + zeros 44..55, 128 rows
constexpr int ST3 = 88;    // act3: 80 ch + bias col 80 + zeros 81..87, 128 rows
constexpr int ST4 = 56;    // act4: like act2, 130 rows (q off +1)

constexpr int SLOTA_OFF = 0;
constexpr int SLOTA_SZ  = 22544;   // act3 extent incl. row-127 ks-spill (11272 u16)
constexpr int SLOTB_OFF = SLOTA_SZ;
constexpr int SLOTB_SZ  = 14576;   // act4 extent incl. row-129 ks-spill (7288 u16)
constexpr int TAIL_OFF  = SLOTB_OFF + SLOTB_SZ;     // 37120
// tail f32: sdif 132 | sw6 20 | sb6 1 | sbm 118 | su 121 = 392
constexpr int SMEM_BYTES = TAIL_OFF + 392 * 4;      // 38688 -> 4 blocks/CU

// precomputed bf16 A-fragments in d_ws (u16 units); frag idx = (t*MT+mt)*KS+ks
constexpr int F2 = 0;          // L2: 5 taps x MT3 x KS1 = 15 frags x 512 u16
constexpr int F3 = 7680;       // L3: 1 x 5 x 2 = 10
constexpr int F4 = 12800;      // L4: 1 x 3 x 3 = 9
constexpr int F5 = 17408;      // L5: 3 x 2 x 2 = 12
constexpr int F1 = 23552;      // L1: 2 frags (MT=2, taps+bias in k)  -> ends 24576
constexpr int NFRAG2 = 15, NFRAG3 = 10, NFRAG4 = 9, NFRAG5 = 12;
constexpr int NPREP = NFRAG2 + NFRAG3 + NFRAG4 + NFRAG5 + 2;   // 48
constexpr int BME_OFF = 65536; // 4 edge bm values (f32): bm[0], bm[1], bm[N-2], bm[N-1]
                               // 0 = "not ready" (bmv > 0.1 always; prep zeroes)

typedef __bf16 bf16x8 __attribute__((ext_vector_type(8)));
typedef unsigned short u16x8 __attribute__((ext_vector_type(8)));
typedef float f32x4 __attribute__((ext_vector_type(4)));

constexpr unsigned short BF16_ONE = 0x3F80;

__device__ __forceinline__ float elu(float x) { return x > 0.f ? x : __expf(x) - 1.f; }

__device__ __forceinline__ float fastrcp(float x) {
#if __has_builtin(__builtin_amdgcn_rcpf)
    return __builtin_amdgcn_rcpf(x);
#else
    return 1.f / x;
#endif
}

// precise RTNE (weights, once in prep)
__device__ __forceinline__ unsigned short f2b_rtne(float f) {
    union { float f; unsigned int u; } x; x.f = f;
    return (unsigned short)((x.u + 0x7fffu + ((x.u >> 16) & 1u)) >> 16);
}
// pack two f32 -> two bf16 (round-half-up) in one dword
__device__ __forceinline__ unsigned int pack_bf16_2(float lo, float hi) {
#if __has_builtin(__builtin_amdgcn_perm)
    union { float f; unsigned int u; } a, b;
    a.f = lo; b.f = hi;
    return __builtin_amdgcn_perm(b.u + 0x8000u, a.u + 0x8000u, 0x07060302u);
#else
    union { float f; unsigned int u; } a, b;
    a.f = lo; b.f = hi;
    return ((a.u + 0x8000u) >> 16) | (((b.u + 0x8000u) >> 16) << 16);
#endif
}

// ---------------------------------------------------------------------------
// Prep: one fragment per block. RTNE, zero-padded m/k.
// Bias folded at k == CI on tap biasTap (activation bias column holds 1.0).
// Block 0 also zeroes the bmE ready-slots (re-armed every launch).
// ---------------------------------------------------------------------------
template<int M, int MT, int CI, int KS, int KT>
__device__ __forceinline__ void pack_one(const float* __restrict__ W,
                                         const float* __restrict__ Bias, int biasTap,
                                         unsigned short* __restrict__ dst,
                                         int f, int lane)
{
    const int ks = f % KS;
    const int fi = f / KS;
    const int mt = fi % MT;
    const int t  = fi / MT;
    const int m  = mt * 16 + (lane & 15);
    const int kb = ks * 32 + (lane >> 4) * 8;
    u16x8 v;
    #pragma unroll
    for (int j = 0; j < 8; ++j) {
        const int k = kb + j;
        float val = 0.f;
        if (m < M) {
            if (k < CI)                          val = W[(m * CI + k) * KT + t];
            else if (k == CI && t == biasTap)    val = Bias[m];
        }
        v[j] = f2b_rtne(val);
    }
    *(u16x8*)(dst + (f * 64 + lane) * 8) = v;
}

__global__ __launch_bounds__(64) void prep_kernel(
    const float* __restrict__ w1, const float* __restrict__ b1,
    const float* __restrict__ w2, const float* __restrict__ b2,
    const float* __restrict__ w3, const float* __restrict__ b3,
    const float* __restrict__ w4, const float* __restrict__ b4,
    const float* __restrict__ w5, const float* __restrict__ b5,
    unsigned short* __restrict__ frags,
    float* __restrict__ bmE)
{
    const int lane = threadIdx.x;
    const int b = blockIdx.x;
    if (b == 0 && lane < 4) bmE[lane] = 0.f;   // "not ready" sentinel
    if (b < NFRAG2)
        pack_one<40, 3, 20, 1, 5>(w2, b2, 2, frags + F2, b, lane);
    else if (b < NFRAG2 + NFRAG3)
        pack_one<80, 5, 40, 2, 1>(w3, b3, 0, frags + F3, b - NFRAG2, lane);
    else if (b < NFRAG2 + NFRAG3 + NFRAG4)
        pack_one<40, 3, 80, 3, 1>(w4, b4, 0, frags + F4, b - NFRAG2 - NFRAG3, lane);
    else if (b < NFRAG2 + NFRAG3 + NFRAG4 + NFRAG5)
        pack_one<20, 2, 40, 2, 3>(w5, b5, 1, frags + F5, b - NFRAG2 - NFRAG3 - NFRAG4, lane);
    else {
        // L1 fragments: A[m][k], k=0..4 -> w1 taps, k=5 -> bias, else 0; im2col B.
        const int mt = b - (NPREP - 2);
        const int m  = mt * 16 + (lane & 15);
        const int kb = (lane >> 4) * 8;
        u16x8 v;
        #pragma unroll
        for (int j = 0; j < 8; ++j) {
            const int k = kb + j;
            float val = 0.f;
            if (m < 20) {
                if (k < 5)      val = w1[m * 5 + k];
                else if (k == 5) val = b1[m];
            }
            v[j] = f2b_rtne(val);
        }
        *(u16x8*)(frags + F1 + (mt * 64 + lane) * 8) = v;
    }
}

// ---------------------------------------------------------------------------
// Tap-decomposed MFMA layer; wave wv owns n-tiles 2wv, 2wv+1.
// A-fragments preloaded to registers. First MFMA consumes the hoisted Z4 quad
// (no per-accumulator zero materialization). Bias via the 1.0 column.
// ---------------------------------------------------------------------------
template<int TAPS, int MT, int KS, typename Epi>
__device__ __forceinline__ void gemm_tap(const unsigned short* __restrict__ Af,
                                         const unsigned short* __restrict__ Bbuf,
                                         int SB, f32x4 Z4, Epi epi)
{
    const int lane = threadIdx.x & 63;
    const int wv   = threadIdx.x >> 6;
    const int n15  = lane & 15;
    const int quad = lane >> 4;

    bf16x8 A[TAPS * MT * KS];
    #pragma unroll
    for (int f = 0; f < TAPS * MT * KS; ++f)
        A[f] = __builtin_bit_cast(bf16x8, *(const u16x8*)(Af + (f * 64 + lane) * 8));

    #pragma unroll
    for (int nt = 0; nt < 2; ++nt) {
        const int pos = (wv * 2 + nt) * 16 + n15;
        bf16x8 B[TAPS][KS];
        #pragma unroll
        for (int t = 0; t < TAPS; ++t)
            #pragma unroll
            for (int ks = 0; ks < KS; ++ks)
                B[t][ks] = __builtin_bit_cast(bf16x8,
                    *(const u16x8*)(Bbuf + (pos + t) * SB + ks * 32 + quad * 8));
        #pragma unroll
        for (int mt = 0; mt < MT; ++mt) {
            f32x4 acc = __builtin_amdgcn_mfma_f32_16x16x32_bf16(
                A[mt * KS], B[0][0], Z4, 0, 0, 0);
            #pragma unroll
            for (int i = 1; i < TAPS * KS; ++i) {
                const int t = i / KS, ks = i - t * KS;
                acc = __builtin_amdgcn_mfma_f32_16x16x32_bf16(
                    A[(t * MT + mt) * KS + ks], B[t][ks], acc, 0, 0, 0);
            }
            epi(mt, pos, acc);
        }
    }
}

// ---------------------------------------------------------------------------
// WENO5 math given the 6-point u stencil and 3 bm values (rcp-based)
// ---------------------------------------------------------------------------
__device__ __forceinline__ float weno_math(float um2, float um1, float u0,
                                           float up1, float up2, float up3,
                                           float bmm, float bm0, float bmp)
{
    const float c1312 = 13.f / 12.f;
    const float s6 = 1.f / 6.f;

    const float f0p = (11.f * up1 - 7.f * up2 + 2.f * up3) * s6;
    const float f1p = (2.f * u0 + 5.f * up1 - up2) * s6;
    const float f2p = (-um1 + 5.f * u0 + 2.f * up1) * s6;
    const float f0n = (11.f * u0 - 7.f * up1 + 2.f * up2) * s6;
    const float f1n = (2.f * um1 + 5.f * u0 - up1) * s6;
    const float f2n = (-um2 + 5.f * um1 + 2.f * u0) * s6;

    float t0, t1;
    t0 = up1 - 2.f * up2 + up3;  t1 = 3.f * up1 - 4.f * up2 + up3;
    float bp0 = c1312 * t0 * t0 + 0.25f * t1 * t1;
    t0 = u0 - 2.f * up1 + up2;   t1 = u0 - up2;
    float bp1 = c1312 * t0 * t0 + 0.25f * t1 * t1;
    t0 = um1 - 2.f * u0 + up1;   t1 = um1 - 4.f * u0 + 3.f * up1;
    float bp2 = c1312 * t0 * t0 + 0.25f * t1 * t1;
    t0 = u0 - 2.f * up1 + up2;   t1 = 3.f * u0 - 4.f * up1 + up2;
    float bn0 = c1312 * t0 * t0 + 0.25f * t1 * t1;
    t0 = um1 - 2.f * u0 + up1;   t1 = um1 - up1;
    float bn1 = c1312 * t0 * t0 + 0.25f * t1 * t1;
    t0 = um2 - 2.f * um1 + u0;   t1 = um2 - 4.f * um1 + 3.f * u0;
    float bn2 = c1312 * t0 * t0 + 0.25f * t1 * t1;

    bp0 *= bmp; bp1 *= bm0; bp2 *= bmm;
    bn0 *= bmp; bn1 *= bm0; bn2 *= bmm;

    const float E = 1e-13f;
    float brs, e, r0, r1, r2, o0, o1, o2;

    brs = bp2 - bp0; brs *= brs;
    e = E + bp0; e *= e; r0 = fastrcp(e);
    e = E + bp1; e *= e; r1 = fastrcp(e);
    e = E + bp2; e *= e; r2 = fastrcp(e);
    o0 = 0.1f * fmaf(brs, r0, 1.f);
    o1 = 0.6f * fmaf(brs, r1, 1.f);
    o2 = 0.3f * fmaf(brs, r2, 1.f);
    const float fluxp = (o0 * f0p + o1 * f1p + o2 * f2p) * fastrcp(o0 + o1 + o2);

    brs = bn2 - bn0; brs *= brs;
    e = E + bn0; e *= e; r0 = fastrcp(e);
    e = E + bn1; e *= e; r1 = fastrcp(e);
    e = E + bn2; e *= e; r2 = fastrcp(e);
    o0 = 0.1f * fmaf(brs, r0, 1.f);
    o1 = 0.6f * fmaf(brs, r1, 1.f);
    o2 = 0.3f * fmaf(brs, r2, 1.f);
    const float fluxn = (o0 * f0n + o1 * f1n + o2 * f2n) * fastrcp(o0 + o1 + o2);

    return fluxp - fluxn;
}

// ---------------------------------------------------------------------------
// Fused CNN + WENO (256 threads = 4 waves; two n-tiles per wave).
// Grid = NBLK + 1: the extra block is a zero-contention tail that waits for
// the 4 edge bm values and patches the two periodic-wrap outputs.
// ---------------------------------------------------------------------------
__global__ __launch_bounds__(BLK, 4) void cnn_weno_kernel(
    const float* __restrict__ u,
    const float* __restrict__ w6, const float* __restrict__ b6,
    const unsigned short* __restrict__ frags,
    float* __restrict__ bmE,
    float* __restrict__ out)
{
    // ---- tail block: spin on the 4 ready-slots, then patch wrap points ----
    if (blockIdx.x == NBLK) {
        if (threadIdx.x == 0) {
            float b0, b1, b2, b3;
            for (;;) {
                b0 = __hip_atomic_load(&bmE[0], __ATOMIC_ACQUIRE, __HIP_MEMORY_SCOPE_AGENT);
                b1 = __hip_atomic_load(&bmE[1], __ATOMIC_ACQUIRE, __HIP_MEMORY_SCOPE_AGENT);
                b2 = __hip_atomic_load(&bmE[2], __ATOMIC_ACQUIRE, __HIP_MEMORY_SCOPE_AGENT);
                b3 = __hip_atomic_load(&bmE[3], __ATOMIC_ACQUIRE, __HIP_MEMORY_SCOPE_AGENT);
                if (b0 != 0.f && b1 != 0.f && b2 != 0.f && b3 != 0.f) break;
                __builtin_amdgcn_s_sleep(2);
            }
            out[0] = weno_math(u[N_PTS - 2], u[N_PTS - 1], u[0],
                               u[1], u[2], u[3], b3, b0, b1);
            out[N_PTS - 1] = weno_math(u[N_PTS - 3], u[N_PTS - 2], u[N_PTS - 1],
                                       u[0], u[1], u[2], b2, b3, b0);
        }
        return;
    }

    extern __shared__ char smem[];
    unsigned short* act1 = (unsigned short*)(smem + SLOTA_OFF);  // [132][ST1]
    unsigned short* act3 = (unsigned short*)(smem + SLOTA_OFF);  // [128][ST3]
    unsigned short* act2 = (unsigned short*)(smem + SLOTB_OFF);  // [128][ST2]
    unsigned short* act4 = (unsigned short*)(smem + SLOTB_OFF);  // [130][ST4]
    float* sdif = (float*)(smem + TAIL_OFF);   // 132
    float* sw6  = sdif + 132;                  // 20
    float* sb6  = sw6 + 20;                    // 1
    float* sbm  = sb6 + 1;                     // 118  (sbm[j] = bm at q = j + 5)
    float* su   = sbm + 118;                   // 121  (su[j] = u[(i0-2+j) & MASK])

    const int tid  = threadIdx.x;
    const int lane = tid & 63;
    const int wv   = tid >> 6;
    const int n15  = lane & 15;
    const int quad = lane >> 4;
    const int i0   = blockIdx.x * POUT;
    const bool edge = (blockIdx.x == 0) || (blockIdx.x >= NBLK - 1);

    const f32x4 Z4 = {0.f, 0.f, 0.f, 0.f};     // hoisted zero C-operand

    // ---- phase 1: pad init + stale-read guards + staging ----
    {
        const u16x8 z8 = {0, 0, 0, 0, 0, 0, 0, 0};
        // SLOTB (act2/act4, ST=56) cols 48..55 zero, rows 0..129.
        for (int r = tid; r < 130; r += BLK)
            *(u16x8*)(act2 + r * ST2 + 48) = z8;
        // Stale-read guards (virgin-LDS NaN immunity): every never-written
        // location that any B-read (incl. ks-spill) touches is zeroed here.
        if (tid < 20)       *(u16x8*)(act1 + 128 * ST1 + tid * 8) = z8;  // act1 rows 128..131
        else if (tid == 20) *(u16x8*)(act2 + 128 * ST2) = z8;            // act2 row 128 c0..7
        else if (tid == 21) *(u16x8*)(act3 + 128 * ST3) = z8;            // act3 row 128 c0..7
        else if (tid < 28)  *(u16x8*)(act4 + 129 * ST4 + (tid - 22) * 8) = z8; // act4 r129 c0..47
        else if (tid == 28) *(u16x8*)(act4 + 130 * ST4) = z8;            // act4 row 130 c0..7
    }
    if (!edge) {   // fast path: no boundary handling needed (uniform branch)
        for (int d = tid; d < 132; d += BLK) {
            const int g = i0 - 10 + d;
            sdif[d] = 0.5f * (u[g + 1] - u[g - 1]);
        }
        for (int j = tid; j < 121; j += BLK)
            su[j] = u[i0 - 2 + j];
    } else {
        for (int d = tid; d < 132; d += BLK) {
            const int g = i0 - 10 + d;
            float v = 0.f;
            if (g >= 0 && g < N_PTS) {
                if (g == 0)              v = u[1] - u[0];
                else if (g == N_PTS - 1) v = u[N_PTS - 1] - u[N_PTS - 2];
                else                     v = 0.5f * (u[g + 1] - u[g - 1]);
            }
            sdif[d] = v;
        }
        for (int j = tid; j < 121; j += BLK)
            su[j] = u[(i0 - 2 + j) & MASK];
    }
    if (tid < 20)       sw6[tid] = w6[tid];
    else if (tid == 20) sb6[0] = b6[0];
    __syncthreads();

    // ---- phase 2: L1 via MFMA (im2col B from sdif; taps+bias in k) ----
    {
        bf16x8 A1[2];
        #pragma unroll
        for (int f = 0; f < 2; ++f)
            A1[f] = __builtin_bit_cast(bf16x8,
                *(const u16x8*)(frags + F1 + (f * 64 + lane) * 8));
        #pragma unroll
        for (int nt = 0; nt < 2; ++nt) {
            const int pos = (wv * 2 + nt) * 16 + n15;
            const float s0 = sdif[pos],     s1 = sdif[pos + 1], s2 = sdif[pos + 2],
                        s3 = sdif[pos + 3], s4 = sdif[pos + 4];
            uint4 bd;
            bd.x = pack_bf16_2(s0, s1);
            bd.y = pack_bf16_2(s2, s3);
            bd.z = pack_bf16_2(s4, 1.0f);    // k=5 bias slot
            bd.w = 0u;
            const bf16x8 B = __builtin_bit_cast(bf16x8, bd);
            const f32x4 a0 = __builtin_amdgcn_mfma_f32_16x16x32_bf16(A1[0], B, Z4, 0, 0, 0);
            const f32x4 a1 = __builtin_amdgcn_mfma_f32_16x16x32_bf16(A1[1], B, Z4, 0, 0, 0);
            bool oor = false;
            if (edge) {
                const int g = i0 + pos - 8;   // act1 row pos <-> g
                oor = ((unsigned)g >= (unsigned)N_PTS);
            }
            {   // ch 0..15
                float v0 = elu(a0[0]), v1 = elu(a0[1]), v2 = elu(a0[2]), v3 = elu(a0[3]);
                if (oor) { v0 = v1 = v2 = v3 = 0.f; }
                uint2 w; w.x = pack_bf16_2(v0, v1); w.y = pack_bf16_2(v2, v3);
                *(uint2*)(act1 + pos * ST1 + quad * 4) = w;
            }
            {   // ch 16..19 + bias col 20 + zero pad 24..31
                uint2 w;
                if (quad == 0) {
                    float v0 = elu(a1[0]), v1 = elu(a1[1]), v2 = elu(a1[2]), v3 = elu(a1[3]);
                    if (oor) { v0 = v1 = v2 = v3 = 0.f; }
                    w.x = pack_bf16_2(v0, v1); w.y = pack_bf16_2(v2, v3);
                } else if (quad == 1) {
                    w.x = (unsigned)BF16_ONE; w.y = 0u;
                } else {
                    w.x = 0u; w.y = 0u;
                }
                *(uint2*)(act1 + pos * ST1 + 16 + quad * 4) = w;
            }
        }
    }
    __syncthreads();

    // ---- phase 3: L2 (40ch, 5 taps, bias folded) act1 -> act2 ----
    gemm_tap<5, 3, 1>(frags + F2, act1, ST1, Z4,
        [&](int mt, int pos, f32x4 acc) {
            const int ch0 = mt * 16 + quad * 4;
            unsigned short* dst = act2 + pos * ST2 + ch0;
            if (mt < 2 || quad < 2) {
                float v0 = elu(acc[0]), v1 = elu(acc[1]), v2 = elu(acc[2]), v3 = elu(acc[3]);
                if (edge) {
                    const int g = i0 - GOFF + pos;
                    if ((unsigned)g >= (unsigned)N_PTS) { v0 = v1 = v2 = v3 = 0.f; }
                }
                uint2 w; w.x = pack_bf16_2(v0, v1); w.y = pack_bf16_2(v2, v3);
                *(uint2*)dst = w;
            } else {   // ch 40 bias col + zeros 41..47
                uint2 w; w.x = (quad == 2) ? (unsigned)BF16_ONE : 0u; w.y = 0u;
                *(uint2*)dst = w;
            }
        });
    __syncthreads();

    // ---- phase 4: act3 bias/pad init (act1 rows 0..48 alias is dead now),
    //      then L3 (80ch, k=1, bias folded) act2 -> act3 ----
    {
        u16x8 v = {BF16_ONE, 0, 0, 0, 0, 0, 0, 0};
        for (int r = tid; r < 128; r += BLK)
            *(u16x8*)(act3 + r * ST3 + 80) = v;
    }
    gemm_tap<1, 5, 2>(frags + F3, act2, ST2, Z4,
        [&](int mt, int pos, f32x4 acc) {
            const int ch0 = mt * 16 + quad * 4;
            float v0 = elu(acc[0]), v1 = elu(acc[1]), v2 = elu(acc[2]), v3 = elu(acc[3]);
            if (edge) {
                const int g = i0 - GOFF + pos;
                if ((unsigned)g >= (unsigned)N_PTS) { v0 = v1 = v2 = v3 = 0.f; }
            }
            uint2 w; w.x = pack_bf16_2(v0, v1); w.y = pack_bf16_2(v2, v3);
            *(uint2*)(act3 + pos * ST3 + ch0) = w;
        });
    __syncthreads();

    // ---- phase 5: L4 (40ch, k=1, bias folded) act3 -> act4 (row off +1) ----
    gemm_tap<1, 3, 3>(frags + F4, act3, ST3, Z4,
        [&](int mt, int pos, f32x4 acc) {
            const int ch0 = mt * 16 + quad * 4;
            unsigned short* dst = act4 + (pos + 1) * ST4 + ch0;
            if (mt < 2 || quad < 2) {
                float v0 = elu(acc[0]), v1 = elu(acc[1]), v2 = elu(acc[2]), v3 = elu(acc[3]);
                if (edge) {
                    const int g = i0 - GOFF + pos;
                    if ((unsigned)g >= (unsigned)N_PTS) { v0 = v1 = v2 = v3 = 0.f; }
                }
                uint2 w; w.x = pack_bf16_2(v0, v1); w.y = pack_bf16_2(v2, v3);
                *(uint2*)dst = w;
            } else {
                uint2 w; w.x = (quad == 2) ? (unsigned)BF16_ONE : 0u; w.y = 0u;
                *(uint2*)dst = w;
            }
        });
    __syncthreads();

    // ---- phase 6: L5 (20ch, 3 taps, bias folded) + L6 + sigmoid -> sbm ----
    {
        const unsigned short* Af = frags + F5;
        bf16x8 A5[12];
        #pragma unroll
        for (int f = 0; f < 12; ++f)
            A5[f] = __builtin_bit_cast(bf16x8, *(const u16x8*)(Af + (f * 64 + lane) * 8));

        #pragma unroll
        for (int nt = 0; nt < 2; ++nt) {
            const int pos = (wv * 2 + nt) * 16 + n15;
            bf16x8 B[3][2];
            #pragma unroll
            for (int t = 0; t < 3; ++t)
                #pragma unroll
                for (int ks = 0; ks < 2; ++ks)
                    B[t][ks] = __builtin_bit_cast(bf16x8,
                        *(const u16x8*)(act4 + (pos + t) * ST4 + ks * 32 + quad * 8));
            f32x4 a0 = __builtin_amdgcn_mfma_f32_16x16x32_bf16(A5[0], B[0][0], Z4, 0, 0, 0);
            f32x4 a1 = __builtin_amdgcn_mfma_f32_16x16x32_bf16(A5[2], B[0][0], Z4, 0, 0, 0);
            #pragma unroll
            for (int i = 1; i < 6; ++i) {
                const int t = i >> 1, ks = i & 1;
                a0 = __builtin_amdgcn_mfma_f32_16x16x32_bf16(
                    A5[(t * 2 + 0) * 2 + ks], B[t][ks], a0, 0, 0, 0);
                a1 = __builtin_amdgcn_mfma_f32_16x16x32_bf16(
                    A5[(t * 2 + 1) * 2 + ks], B[t][ks], a1, 0, 0, 0);
            }
            float partial = 0.f;
            const int c0 = quad * 4;
            #pragma unroll
            for (int r = 0; r < 4; ++r)
                partial += sw6[c0 + r] * elu(a0[r]);
            if (quad == 0) {
                #pragma unroll
                for (int r = 0; r < 4; ++r)
                    partial += sw6[16 + r] * elu(a1[r]);
            }
            partial += __shfl_xor(partial, 16, 64);
            partial += __shfl_xor(partial, 32, 64);
            if (quad == 0) {
                const float bmv = fastrcp(1.f + __expf(-(partial + sb6[0]))) + 0.1f;
                if (pos >= 5 && pos < 123) sbm[pos - 5] = bmv;
                if (edge) {
                    const int g = i0 - GOFF + pos;
                    if (blockIdx.x == 0) {
                        if (g == 0)
                            __hip_atomic_store(&bmE[0], bmv, __ATOMIC_RELEASE, __HIP_MEMORY_SCOPE_AGENT);
                        else if (g == 1)
                            __hip_atomic_store(&bmE[1], bmv, __ATOMIC_RELEASE, __HIP_MEMORY_SCOPE_AGENT);
                    }
                    if (blockIdx.x == NBLK - 1) {
                        if (g == N_PTS - 2)
                            __hip_atomic_store(&bmE[2], bmv, __ATOMIC_RELEASE, __HIP_MEMORY_SCOPE_AGENT);
                        else if (g == N_PTS - 1)
                            __hip_atomic_store(&bmE[3], bmv, __ATOMIC_RELEASE, __HIP_MEMORY_SCOPE_AGENT);
                    }
                }
            }
        }
    }
    __syncthreads();

    // ---- phase 7: WENO from the staged u tile (wrap handled at staging) ----
    if (tid < POUT) {
        const int g = i0 + tid;
        if (g < N_PTS && g != 0 && g != N_PTS - 1) {
            out[g] = weno_math(su[tid], su[tid + 1], su[tid + 2],
                               su[tid + 3], su[tid + 4], su[tid + 5],
                               sbm[tid], sbm[tid + 1], sbm[tid + 2]);
        }
    }
}

extern "C" void kernel_launch(void* const* d_in, const int* in_sizes, int n_in,
                              void* d_out, int out_size, void* d_ws, size_t ws_size,
                              hipStream_t stream) {
    const float* u  = (const float*)d_in[0];
    const float* w1 = (const float*)d_in[1];
    const float* b1 = (const float*)d_in[2];
    const float* w2 = (const float*)d_in[3];
    const float* b2 = (const float*)d_in[4];
    const float* w3 = (const float*)d_in[5];
    const float* b3 = (const float*)d_in[6];
    const float* w4 = (const float*)d_in[7];
    const float* b4 = (const float*)d_in[8];
    const float* w5 = (const float*)d_in[9];
    const float* b5 = (const float*)d_in[10];
    const float* w6 = (const float*)d_in[11];
    const float* b6 = (const float*)d_in[12];

    unsigned short* frags = (unsigned short*)d_ws;            // 49152 B
    float* bmE = (float*)((char*)d_ws + BME_OFF);             // 4 f32 ready-slots

    (void)hipFuncSetAttribute((const void*)cnn_weno_kernel,
                              hipFuncAttributeMaxDynamicSharedMemorySize,
                              SMEM_BYTES);

    prep_kernel<<<NPREP, 64, 0, stream>>>(w1, b1, w2, b2, w3, b3, w4, b4, w5, b5,
                                          frags, bmE);
    cnn_weno_kernel<<<NBLK + 1, BLK, SMEM_BYTES, stream>>>(u, w6, b6, frags, bmE,
                                                           (float*)d_out);
}